// Round 3
// baseline (449.125 us; speedup 1.0000x reference)
//
#include <hip/hip_runtime.h>
#include <hip/hip_bf16.h>

// Problem constants (B=8, L=8192, C=256, PE=96, R=90, UP=4, OUT=256)
#define M_TOTAL 65536   // B*L
#define N_TOTAL 1024    // OUT*UP
#define K_TOTAL 448     // C + 2*PE
#define K_PE    192     // PE columns (96 sin + 96 const-PE)
#define R_PE    90

typedef __bf16 bf16x8 __attribute__((ext_vector_type(8)));
typedef __bf16 bf16x4 __attribute__((ext_vector_type(4)));
typedef float  floatx4 __attribute__((ext_vector_type(4)));

// ---------------------------------------------------------------------------
// async global->LDS, 16B per lane. LDS dest = wave-uniform base + lane*16.
// ---------------------------------------------------------------------------
__device__ __forceinline__ void g2lds16(const void* g, void* l) {
    __builtin_amdgcn_global_load_lds(
        (const __attribute__((address_space(1))) void*)g,
        (__attribute__((address_space(3))) void*)l,
        16, 0, 0);
}

// ---------------------------------------------------------------------------
// cpe [3][96][90] -> cpeT [3][90][96] so the per-row d-gather is coalesced.
// ---------------------------------------------------------------------------
__global__ __launch_bounds__(256) void transpose_cpe(
    const float* __restrict__ cpe, float* __restrict__ cpeT)
{
    int i = blockIdx.x * 256 + threadIdx.x;
    if (i < 3 * 96 * R_PE) {
        int c = i / (96 * R_PE);
        int rem = i % (96 * R_PE);
        int d = rem / R_PE;
        int r = rem % R_PE;
        cpeT[((size_t)c * R_PE + r) * 96 + d] = cpe[i];
    }
}

// ---------------------------------------------------------------------------
// PE-only stage: pe[m, 0:192] = [sin(LFF(pc[m])), constPE(pc[m])] (bf16)
// One row per wave; pc loads are lane-uniform (broadcast); gathers coalesced.
// ---------------------------------------------------------------------------
__global__ __launch_bounds__(256) void build_pe(
    const float* __restrict__ pc,     // [65536, 3]
    const float* __restrict__ lff_w,  // [96, 3]
    const float* __restrict__ lff_b,  // [96]
    const float* __restrict__ cpeT,   // [3, 90, 96] (transposed)
    __bf16* __restrict__ pe)          // [65536, 192]
{
    const int wave = threadIdx.x >> 6;
    const int lane = threadIdx.x & 63;

    const float w00 = lff_w[lane * 3 + 0];
    const float w01 = lff_w[lane * 3 + 1];
    const float w02 = lff_w[lane * 3 + 2];
    const float bb0 = lff_b[lane];
    float w10 = 0.f, w11 = 0.f, w12 = 0.f, bb1 = 0.f;
    if (lane < 32) {
        w10 = lff_w[(64 + lane) * 3 + 0];
        w11 = lff_w[(64 + lane) * 3 + 1];
        w12 = lff_w[(64 + lane) * 3 + 2];
        bb1 = lff_b[64 + lane];
    }

    for (int m = blockIdx.x * 4 + wave; m < M_TOTAL; m += gridDim.x * 4) {
        const float p0 = pc[m * 3 + 0];
        const float p1 = pc[m * 3 + 1];
        const float p2 = pc[m * 3 + 2];
        __bf16* row = pe + (size_t)m * K_PE;

        // ---- lpe: sin(pc . w + b) ----
        float a0 = fmaf(p2, w02, fmaf(p1, w01, fmaf(p0, w00, bb0)));
        row[lane] = (__bf16)__sinf(a0);
        if (lane < 32) {
            float a1 = fmaf(p2, w12, fmaf(p1, w11, fmaf(p0, w10, bb1)));
            row[64 + lane] = (__bf16)__sinf(a1);
        }

        // ---- cpe: bilinear over transposed table ----
        const float pch[3] = { p0, p1, p2 };
        const float* tab0[3];
        const float* tab1[3];
        float m0[3], m1[3];
        #pragma unroll
        for (int c = 0; c < 3; ++c) {
            float ix = (pch[c] + 1.f) * 45.f - 0.5f;   // ((p+1)*R-1)*0.5
            float fl = floorf(ix);
            float w  = ix - fl;
            int   i0 = (int)fl;
            bool  ok0 = (i0 >= 0) && (i0 < R_PE);
            bool  ok1 = (i0 + 1 >= 0) && (i0 + 1 < R_PE);
            int   c0 = ok0 ? i0 : 0;
            int   c1 = ok1 ? i0 + 1 : 0;
            tab0[c] = cpeT + ((size_t)c * R_PE + c0) * 96;
            tab1[c] = cpeT + ((size_t)c * R_PE + c1) * 96;
            m0[c] = ok0 ? (1.f - w) : 0.f;
            m1[c] = ok1 ? w : 0.f;
        }
        float acc0 = 0.f;
        #pragma unroll
        for (int c = 0; c < 3; ++c)
            acc0 += m0[c] * tab0[c][lane] + m1[c] * tab1[c][lane];
        row[96 + lane] = (__bf16)(acc0 * 0.57735026918962576f);  // 1/sqrt(3)
        if (lane < 32) {
            float acc1 = 0.f;
            #pragma unroll
            for (int c = 0; c < 3; ++c)
                acc1 += m0[c] * tab0[c][64 + lane] + m1[c] * tab1[c][64 + lane];
            row[96 + 64 + lane] = (__bf16)(acc1 * 0.57735026918962576f);
        }
    }
}

// ---------------------------------------------------------------------------
// sub_w [1024,448] f32 -> bf16 (already B^T layout: N-major, K-contiguous)
// ---------------------------------------------------------------------------
__global__ __launch_bounds__(256) void convert_w(
    const float* __restrict__ w, __bf16* __restrict__ wb)
{
    int i = (blockIdx.x * 256 + threadIdx.x) * 4;
    if (i < N_TOTAL * K_TOTAL) {
        float4 v = *(const float4*)(w + i);
        bf16x4 o = { (__bf16)v.x, (__bf16)v.y, (__bf16)v.z, (__bf16)v.w };
        *(bf16x4*)(wb + i) = o;
    }
}

// ---------------------------------------------------------------------------
// pc_up: repeat_interleave(pc, 4, axis=1)
// ---------------------------------------------------------------------------
__global__ __launch_bounds__(256) void pc_up_kernel(
    const float* __restrict__ pc, float* __restrict__ out2)
{
    int e = blockIdx.x * 256 + threadIdx.x;
    if (e < M_TOTAL * 12) {
        int m = e / 12;
        int j = e % 3;
        out2[e] = pc[m * 3 + j];
    }
}

// ---------------------------------------------------------------------------
// Fused GEMM: C[m,n] = sum_k xpe[m,k] * sub_w[n,k] with xpe built on the fly:
//   k in [0,256)  : bf16(X[m,k])  -- reg-staged f32->bf16, ds_write
//   k in [256,448): PE[m,k-256]   -- global_load_lds (pre-swizzled source)
// Sync scheme = R1's PROVEN drain pipeline (single tile in flight):
//   issue tile t+1 -> compute tile t -> vmcnt(0) -> writeX(t+1) -> lgkmcnt(0)
//   -> barrier (publishes t+1, frees buf of t).  One barrier per K-step; no
//   counted-vmcnt issue-order assumptions (the R2 NaN bug).
// ---------------------------------------------------------------------------
__global__ __launch_bounds__(256) void gemm_fused(
    const float* __restrict__ X,     // [65536, 256] f32 (A k<256 + residual)
    const __bf16* __restrict__ PE,   // [65536, 192] bf16
    const __bf16* __restrict__ Bw,   // [1024, 448] bf16
    const float* __restrict__ bias,  // [1024]
    float* __restrict__ out)         // x_up part of d_out
{
    __shared__ __attribute__((aligned(16))) __bf16 As[2][128 * 64];  // 2 x 16 KB
    __shared__ __attribute__((aligned(16))) __bf16 Bs[2][128 * 64];  // 2 x 16 KB

    const int tid  = threadIdx.x;
    const int wave = tid >> 6;
    const int lane = tid & 63;
    const int quad = lane >> 4;
    const int l16  = lane & 15;
    const int wm   = (wave >> 1) * 64;
    const int wn   = (wave & 1) * 64;

    // XCD-aware swizzle: each XCD owns 64 M-tiles; the 8 N-blocks of one
    // M-tile are dispatched consecutively on that XCD (A/X L2 reuse x8).
    const unsigned bx = blockIdx.x;
    const int bm = (int)(((bx & 7u) * 64u + (bx >> 6)) * 128u);
    const int bn = (int)(((bx >> 3) & 7u) * 128u);

    floatx4 acc[4][4];
    #pragma unroll
    for (int i = 0; i < 4; ++i)
        #pragma unroll
        for (int j = 0; j < 4; ++j)
            acc[i][j] = (floatx4){0.f, 0.f, 0.f, 0.f};

    float4 xr[2][8];   // two static reg sets (rule #20): tile parity

    auto stageB = [&](int buf, int tt) {            // 4 x g2lds16
        const int kt = tt * 64;
        #pragma unroll
        for (int s = 0; s < 4; ++s) {
            const int idx = s * 256 + tid;
            const int r   = idx >> 3;
            const int cs  = (idx & 7) ^ (r & 7);    // pre-swizzled source chunk
            g2lds16(Bw + (size_t)(bn + r) * K_TOTAL + kt + cs * 8,
                    &Bs[buf][(size_t)(s * 256 + wave * 64) * 8]);
        }
    };
    auto stageA_pe = [&](int buf, int tt) {         // tt>=4, 4 x g2lds16
        const int kp = tt * 64 - 256;
        #pragma unroll
        for (int s = 0; s < 4; ++s) {
            const int idx = s * 256 + tid;
            const int r   = idx >> 3;
            const int cs  = (idx & 7) ^ (r & 7);
            g2lds16(PE + (size_t)(bm + r) * K_PE + kp + cs * 8,
                    &As[buf][(size_t)(s * 256 + wave * 64) * 8]);
        }
    };
    auto loadX = [&](float4* xr8, int tt) {         // tt<4, 8 x dwordx4 -> regs
        const int kt = tt * 64;
        #pragma unroll
        for (int s = 0; s < 4; ++s) {
            const int idx = s * 256 + tid;
            const int r   = idx >> 3;
            const int cs  = (idx & 7) ^ (r & 7);    // swizzled source col
            const float* src = X + (size_t)(bm + r) * 256 + kt + cs * 8;
            xr8[s * 2]     = *(const float4*)src;
            xr8[s * 2 + 1] = *(const float4*)(src + 4);
        }
    };
    auto writeX = [&](int buf, const float4* xr8) { // cvt + 4 x ds_write_b128
        #pragma unroll
        for (int s = 0; s < 4; ++s) {
            const int idx = s * 256 + tid;          // linear LDS slot
            float4 a = xr8[s * 2];
            float4 b = xr8[s * 2 + 1];
            bf16x8 o = { (__bf16)a.x, (__bf16)a.y, (__bf16)a.z, (__bf16)a.w,
                         (__bf16)b.x, (__bf16)b.y, (__bf16)b.z, (__bf16)b.w };
            *(bf16x8*)(&As[buf][(size_t)idx * 8]) = o;
        }
    };

    // ---- prologue: stage tile 0 fully, publish ----
    loadX(xr[0], 0);
    stageB(0, 0);
    asm volatile("s_waitcnt vmcnt(0)" ::: "memory");
    writeX(0, xr[0]);
    asm volatile("s_waitcnt lgkmcnt(0)" ::: "memory");
    __builtin_amdgcn_s_barrier();

    #pragma unroll
    for (int t = 0; t < 7; ++t) {
        const int cur = t & 1;

        // issue tile t+1 into buf cur^1 (overlaps with compute below)
        if (t < 3)      { loadX(xr[(t + 1) & 1], t + 1); stageB(cur ^ 1, t + 1); }
        else if (t < 6) { stageA_pe(cur ^ 1, t + 1);     stageB(cur ^ 1, t + 1); }

        // compute on buf cur
        #pragma unroll
        for (int s = 0; s < 2; ++s) {
            bf16x8 af[4], bfr[4];
            #pragma unroll
            for (int i = 0; i < 4; ++i) {
                const int row = wm + i * 16 + l16;
                const int ch  = (s * 4 + quad) ^ (row & 7);   // read-side swizzle
                af[i] = *(const bf16x8*)(&As[cur][row * 64 + ch * 8]);
            }
            #pragma unroll
            for (int j = 0; j < 4; ++j) {
                const int row = wn + j * 16 + l16;
                const int ch  = (s * 4 + quad) ^ (row & 7);
                bfr[j] = *(const bf16x8*)(&Bs[cur][row * 64 + ch * 8]);
            }
            __builtin_amdgcn_s_setprio(1);
            #pragma unroll
            for (int i = 0; i < 4; ++i)
                #pragma unroll
                for (int j = 0; j < 4; ++j)
                    acc[i][j] = __builtin_amdgcn_mfma_f32_16x16x32_bf16(
                        af[i], bfr[j], acc[i][j], 0, 0, 0);
            __builtin_amdgcn_s_setprio(0);
        }

        // drain tile t+1 loads (latency was hidden under compute), publish
        if (t < 6) {
            asm volatile("s_waitcnt vmcnt(0)" ::: "memory");
            if (t < 3) writeX(cur ^ 1, xr[(t + 1) & 1]);
            asm volatile("s_waitcnt lgkmcnt(0)" ::: "memory");
            __builtin_amdgcn_s_barrier();   // publishes t+1; frees buf cur
        }
    }

    // ---- fused epilogue ----
    const float gain = 0.047245559126153576f;     // 1/sqrt(448)
    const float inv_sqrt2 = 0.70710678118654752f;
    #pragma unroll
    for (int i = 0; i < 4; ++i) {
        #pragma unroll
        for (int j = 0; j < 4; ++j) {
            const int n = bn + wn + j * 16 + l16;
            const float bs = bias[n];
            const int o = n & 255;
            const int u = n >> 8;
            #pragma unroll
            for (int r = 0; r < 4; ++r) {
                const int m = bm + wm + i * 16 + quad * 4 + r;
                float y = acc[i][j][r] * gain + bs;
                float act = (y >= 0.f) ? y : 0.2f * y;   // lrelu*sqrt2 /sqrt2 == 1
                float res = X[(size_t)m * 256 + o];      // L2-warm (staged above)
                out[((size_t)(m * 4 + u)) * 256 + o] = fmaf(res, inv_sqrt2, act);
            }
        }
    }
}

// ---------------------------------------------------------------------------
extern "C" void kernel_launch(void* const* d_in, const int* in_sizes, int n_in,
                              void* d_out, int out_size, void* d_ws, size_t ws_size,
                              hipStream_t stream) {
    const float* X      = (const float*)d_in[0];  // [8,8192,256]
    const float* pc     = (const float*)d_in[1];  // [8,8192,3]
    const float* lff_w  = (const float*)d_in[2];  // [96,3]
    const float* lff_b  = (const float*)d_in[3];  // [96]
    const float* cpe    = (const float*)d_in[4];  // [3,96,90]
    const float* sub_w  = (const float*)d_in[5];  // [1024,448]
    const float* sub_b  = (const float*)d_in[6];  // [1024]

    float* out    = (float*)d_out;                       // x_up: 67108864 floats
    float* out_pc = out + (size_t)M_TOTAL * 4 * 256;     // pc_up: 786432 floats

    // workspace: PE bf16 [65536,192], sub_w bf16 [1024,448], cpeT f32 [3,90,96]
    __bf16* pe   = (__bf16*)d_ws;
    __bf16* wb   = (__bf16*)((char*)d_ws + (size_t)M_TOTAL * K_PE * 2);
    float*  cpeT = (float*)((char*)d_ws + (size_t)M_TOTAL * K_PE * 2
                                        + (size_t)N_TOTAL * K_TOTAL * 2);

    convert_w    <<<448,  256, 0, stream>>>(sub_w, wb);
    pc_up_kernel <<<3072, 256, 0, stream>>>(pc, out_pc);
    transpose_cpe<<<102,  256, 0, stream>>>(cpe, cpeT);
    build_pe     <<<4096, 256, 0, stream>>>(pc, lff_w, lff_b, cpeT, pe);
    gemm_fused   <<<4096, 256, 0, stream>>>(X, pe, wb, sub_b, out);
}